// Round 1
// 389.195 us; speedup vs baseline: 1.0278x; 1.0278x over previous
//
#include <hip/hip_runtime.h>
#include <hip/hip_bf16.h>
#include <stdint.h>

typedef __attribute__((ext_vector_type(8))) short s16x8;    // bf16 MFMA A/B frag (4 VGPRs)
typedef __attribute__((ext_vector_type(4))) float f32x4;    // MFMA C/D frag
typedef __attribute__((ext_vector_type(8))) unsigned short us8;
typedef __attribute__((ext_vector_type(4))) unsigned short us4;

// ---- bf16 round-to-nearest-even (inputs are finite normals) ----
__device__ inline unsigned short bf_rne(float f) {
    union { float f; uint32_t u; } v; v.f = f;
    uint32_t u = v.u;
    u += 0x7FFFu + ((u >> 16) & 1u);
    return (unsigned short)(u >> 16);
}

// async global->LDS, 16B per lane; LDS dst is wave-uniform base + lane*16
#define GLD_LDS16(gp, lp)                                                     \
    __builtin_amdgcn_global_load_lds(                                         \
        (const __attribute__((address_space(1))) void*)(gp),                  \
        (__attribute__((address_space(3))) void*)(lp), 16, 0, 0)

// ---------------- Fused prologue (unchanged: at memory roofline) ----------------
// blocks [0,512):    prep — adapted = W + B@A -> bf16, scale = mag/rownorm, 8 rows/block
// blocks [512,8704): cvt — x fp32 -> bf16, 16 elems/thread, lane-coalesced
__global__ __launch_bounds__(256) void prologue_kernel(
    const float4* __restrict__ x4, us4* __restrict__ xbf4,
    const float4* __restrict__ W4,
    const float4* __restrict__ A4,   // [16][1024] float4
    const float* __restrict__ B,     // [4096][16]
    const float* __restrict__ mag,   // [4096]
    unsigned short* __restrict__ wbf,
    float* __restrict__ scale) {
    const int tid = threadIdx.x;
    if (blockIdx.x < 512) {
        const int m0 = blockIdx.x * 8;
        __shared__ float Bs[8][16];
        __shared__ float red[32];
        if (tid < 128) Bs[tid >> 4][tid & 15] = B[m0 * 16 + tid];
        __syncthreads();
        float ss[8] = {};
        for (int c = tid; c < 1024; c += 256) {
            float4 a[16];
#pragma unroll
            for (int r = 0; r < 16; ++r) a[r] = A4[r * 1024 + c];
#pragma unroll
            for (int i = 0; i < 8; ++i) {
                float4 w = W4[(size_t)(m0 + i) * 1024 + c];
#pragma unroll
                for (int r = 0; r < 16; ++r) {
                    const float br = Bs[i][r];
                    w.x += br * a[r].x; w.y += br * a[r].y;
                    w.z += br * a[r].z; w.w += br * a[r].w;
                }
                ss[i] += w.x * w.x + w.y * w.y + w.z * w.z + w.w * w.w;
                us4 o; o[0] = bf_rne(w.x); o[1] = bf_rne(w.y);
                o[2] = bf_rne(w.z); o[3] = bf_rne(w.w);
                *(us4*)&wbf[(size_t)(m0 + i) * 4096 + c * 4] = o;
            }
        }
        const int lane = tid & 63, wv = tid >> 6;
#pragma unroll
        for (int i = 0; i < 8; ++i) {
            float v = ss[i];
#pragma unroll
            for (int off = 32; off > 0; off >>= 1) v += __shfl_down(v, off, 64);
            if (lane == 0) red[wv * 8 + i] = v;
        }
        __syncthreads();
        if (tid < 8) {
            float tot = red[tid] + red[8 + tid] + red[16 + tid] + red[24 + tid];
            scale[m0 + tid] = mag[m0 + tid] / sqrtf(tot);
        }
    } else {
        const size_t base = (size_t)(blockIdx.x - 512) * 1024 + tid;
#pragma unroll
        for (int j = 0; j < 4; ++j) {
            const size_t idx = base + j * 256;
            float4 a = x4[idx];
            us4 o;
            o[0] = bf_rne(a.x); o[1] = bf_rne(a.y);
            o[2] = bf_rne(a.z); o[3] = bf_rne(a.w);
            xbf4[idx] = o;
        }
    }
}

// ---------------- GEMM: C[8192][4096] = xbf @ wbf^T * scale ----------------
// 256x256 tile, BK=64, 8 waves (2M x 4N), 8-phase schedule (T3+T4+T5 per the
// 256^2 template): 4 phases per K-tile, one C-quadrant + one half-tile stage
// per phase, counted vmcnt(4) (never 0 in main loop), raw s_barrier, setprio
// around MFMA clusters. XOR-swizzled LDS (conflict-free, carried from R1).
// Wait ledger (steady state, stage stream per tile = [A0,B0,B1,A1]):
//  - ph1 VMW4 -> cur.B1 landed (needed ph2)
//  - ph2 VMW4 -> cur.A1 landed (needed ph3)
//  - ph3 no wait (ph4 re-reads cur.B0, landed since ph1)
//  - ph4 VMW4 -> next.A0,B0 landed (needed next ph1); 2 half-tiles in flight
// Overwrite safety: stages target buffer d^1, whose last reader drained
// lgkmcnt(0) + crossed >=1 barrier in the previous tile.
#define FENCE() asm volatile("" ::: "memory")
#define BAR()   do { FENCE(); __builtin_amdgcn_s_barrier(); FENCE(); } while (0)
#define VMW4()  asm volatile("s_waitcnt vmcnt(4)" ::: "memory")
#define VMW0()  asm volatile("s_waitcnt vmcnt(0)" ::: "memory")
#define LGW0()  asm volatile("s_waitcnt lgkmcnt(0)" ::: "memory")

__global__ __launch_bounds__(512, 2) void dora_gemm(
    const unsigned short* __restrict__ xbf,   // [8192][4096] bf16
    const unsigned short* __restrict__ wbf,   // [4096][4096] bf16
    const float* __restrict__ scale,          // [4096]
    float* __restrict__ out) {                // [8192][4096] fp32
    __shared__ __align__(16) unsigned short As[2][256 * 64];
    __shared__ __align__(16) unsigned short Bs[2][256 * 64];

    const int tid  = threadIdx.x;
    const int lane = tid & 63;
    const int w    = tid >> 6;     // wave 0..7
    const int wm   = w >> 2;       // 0..1
    const int wn   = w & 3;        // 0..3
    const int q    = lane >> 4;
    const int c15  = lane & 15;

    // XCD swizzle: 512 blocks, 8 XCDs, 64 contiguous wgs per XCD (bijective).
    // wg -> (M-major, 2 N-cols per XCD chunk): W panels (2x2MB) fit per-XCD L2.
    const int bid   = blockIdx.x;
    const int wg    = (bid & 7) * 64 + (bid >> 3);
    const int tileM = (wg & 31) * 256;   // 32 M-tiles
    const int tileN = (wg >> 5) * 256;   // 16 N-tiles

    // staging: thread t, load j covers linear chunk c = j*512 + t of a half-tile
    // (128 rows x 64 bf16). row-in-half = c>>3, phys 16B chunk = c&7; XOR swizzle:
    // phys chunk p of row r holds logical chunk p ^ (r&7) -> pre-swizzled source.
    const int r0 = tid >> 3;              // 0..63
    const int lc = (tid & 7) ^ (r0 & 7);
    const size_t aoff = (size_t)(tileM + r0) * 4096 + lc * 8;
    const size_t boff = (size_t)(tileN + r0) * 4096 + lc * 8;
    const int ld0 = (w * 64) * 8;         // shorts; wave-uniform LDS base, j=0
    const int ld1 = (512 + w * 64) * 8;   // j=1 (+64 rows)

#define STAGE_A(d, h, k0) do {                                                            \
    GLD_LDS16(xbf + aoff + (size_t)((h) * 128) * 4096 + (k0),      &As[d][(h) * 8192 + ld0]); \
    GLD_LDS16(xbf + aoff + (size_t)((h) * 128 + 64) * 4096 + (k0), &As[d][(h) * 8192 + ld1]); \
} while (0)
#define STAGE_B(d, h, k0) do {                                                            \
    GLD_LDS16(wbf + boff + (size_t)((h) * 128) * 4096 + (k0),      &Bs[d][(h) * 8192 + ld0]); \
    GLD_LDS16(wbf + boff + (size_t)((h) * 128 + 64) * 4096 + (k0), &Bs[d][(h) * 8192 + ld1]); \
} while (0)

    s16x8 af[4][2];   // A frags for current mh (held across 2 phases)
    s16x8 bfr[2][2];  // B frags for current nh
    f32x4 acc[8][4] = {};

#define READ_A(d, mh) do {                                                    \
    _Pragma("unroll") for (int mt = 0; mt < 4; ++mt) {                        \
        const int row = (mh) * 128 + wm * 64 + mt * 16 + c15;                 \
        _Pragma("unroll") for (int kc = 0; kc < 2; ++kc) {                    \
            const int phys = (kc * 4 + q) ^ (c15 & 7);                        \
            af[mt][kc] = *(const s16x8*)&As[d][row * 64 + phys * 8];          \
        } } } while (0)
#define READ_B(d, nh) do {                                                    \
    _Pragma("unroll") for (int nt = 0; nt < 2; ++nt) {                        \
        const int row = (nh) * 128 + wn * 32 + nt * 16 + c15;                 \
        _Pragma("unroll") for (int kc = 0; kc < 2; ++kc) {                    \
            const int phys = (kc * 4 + q) ^ (c15 & 7);                        \
            bfr[nt][kc] = *(const s16x8*)&Bs[d][row * 64 + phys * 8];         \
        } } } while (0)
#define MFMA_Q(mh, nh) do {                                                   \
    _Pragma("unroll") for (int mt = 0; mt < 4; ++mt)                          \
    _Pragma("unroll") for (int nt = 0; nt < 2; ++nt)                          \
    _Pragma("unroll") for (int kc = 0; kc < 2; ++kc)                          \
        acc[(mh) * 4 + mt][(nh) * 2 + nt] =                                   \
            __builtin_amdgcn_mfma_f32_16x16x32_bf16(                          \
                af[mt][kc], bfr[nt][kc], acc[(mh) * 4 + mt][(nh) * 2 + nt],   \
                0, 0, 0);                                                     \
} while (0)

    // prologue: stage tile 0 into buf 0 in first-need order; leave 2 half-tiles in flight
    STAGE_A(0, 0, 0); STAGE_B(0, 0, 0); STAGE_B(0, 1, 0); STAGE_A(0, 1, 0);
    VMW4(); BAR();

    for (int t = 0; t < 63; ++t) {
        const int d  = t & 1;
        const int kn = (t + 1) * 64;
        // Phase 1: Q(0,0) — 12 ds_read
        READ_A(d, 0); READ_B(d, 0);
        STAGE_A(d ^ 1, 0, kn);
        VMW4(); BAR(); LGW0();
        __builtin_amdgcn_s_setprio(1); MFMA_Q(0, 0); __builtin_amdgcn_s_setprio(0);
        BAR();
        // Phase 2: Q(0,1) — 4 ds_read (A held)
        READ_B(d, 1);
        STAGE_B(d ^ 1, 0, kn);
        VMW4(); BAR(); LGW0();
        __builtin_amdgcn_s_setprio(1); MFMA_Q(0, 1); __builtin_amdgcn_s_setprio(0);
        BAR();
        // Phase 3: Q(1,1) — 8 ds_read (B held)
        READ_A(d, 1);
        STAGE_B(d ^ 1, 1, kn);
        BAR(); LGW0();
        __builtin_amdgcn_s_setprio(1); MFMA_Q(1, 1); __builtin_amdgcn_s_setprio(0);
        BAR();
        // Phase 4: Q(1,0) — 4 ds_read (B0 re-read; landed since ph1)
        READ_B(d, 0);
        STAGE_A(d ^ 1, 1, kn);
        VMW4(); BAR(); LGW0();
        __builtin_amdgcn_s_setprio(1); MFMA_Q(1, 0); __builtin_amdgcn_s_setprio(0);
        BAR();
    }
    // peeled last tile (t = 63, buf 1): no staging left, drain and compute
    VMW0(); BAR();
    READ_A(1, 0); READ_B(1, 0); MFMA_Q(0, 0);
    READ_B(1, 1);               MFMA_Q(0, 1);
    READ_A(1, 1);               MFMA_Q(1, 1);
    READ_B(1, 0);               MFMA_Q(1, 0);

    // epilogue: C/D layout col=lane&15, row=(lane>>4)*4+reg ; scale by mag/norm
#pragma unroll
    for (int nh = 0; nh < 2; ++nh)
#pragma unroll
    for (int nt = 0; nt < 2; ++nt) {
        const int col = tileN + nh * 128 + wn * 32 + nt * 16 + c15;
        const float s = scale[col];
#pragma unroll
        for (int mh = 0; mh < 2; ++mh)
#pragma unroll
        for (int mt = 0; mt < 4; ++mt) {
            const int row0 = tileM + mh * 128 + wm * 64 + mt * 16 + q * 4;
#pragma unroll
            for (int r = 0; r < 4; ++r)
                out[(size_t)(row0 + r) * 4096 + col] = acc[mh * 4 + mt][nh * 2 + nt][r] * s;
        }
    }
}

extern "C" void kernel_launch(void* const* d_in, const int* in_sizes, int n_in,
                              void* d_out, int out_size, void* d_ws, size_t ws_size,
                              hipStream_t stream) {
    const float* x   = (const float*)d_in[0];   // [4,2048,4096]
    const float* W   = (const float*)d_in[1];   // [4096,4096]
    const float* A   = (const float*)d_in[2];   // [16,4096]
    const float* B   = (const float*)d_in[3];   // [4096,16]
    const float* mag = (const float*)d_in[4];   // [4096]
    float* out = (float*)d_out;

    const size_t XBF_BYTES = (size_t)8192 * 4096 * 2;  // 67,108,864
    const size_t WBF_BYTES = (size_t)4096 * 4096 * 2;  // 33,554,432
    const size_t NEEDED = XBF_BYTES + WBF_BYTES + 4096 * sizeof(float);
    if (ws_size < NEEDED) return;

    unsigned short* xbf = (unsigned short*)d_ws;
    unsigned short* wbf = (unsigned short*)((char*)d_ws + XBF_BYTES);
    float* scale = (float*)((char*)d_ws + XBF_BYTES + WBF_BYTES);

    prologue_kernel<<<8704, 256, 0, stream>>>((const float4*)x, (us4*)xbf,
                                              (const float4*)W, (const float4*)A,
                                              B, mag, wbf, scale);
    dora_gemm<<<512, 512, 0, stream>>>(xbf, wbf, scale, out);
}

// Round 2
// 357.360 us; speedup vs baseline: 1.1194x; 1.0891x over previous
//
#include <hip/hip_runtime.h>
#include <hip/hip_bf16.h>
#include <stdint.h>

typedef __attribute__((ext_vector_type(8))) short s16x8;    // bf16 MFMA A/B frag (4 VGPRs)
typedef __attribute__((ext_vector_type(4))) float f32x4;    // MFMA C/D frag
typedef __attribute__((ext_vector_type(8))) unsigned short us8;
typedef __attribute__((ext_vector_type(4))) unsigned short us4;

// ---- bf16 round-to-nearest-even (inputs are finite normals) ----
__device__ inline unsigned short bf_rne(float f) {
    union { float f; uint32_t u; } v; v.f = f;
    uint32_t u = v.u;
    u += 0x7FFFu + ((u >> 16) & 1u);
    return (unsigned short)(u >> 16);
}

// async global->LDS, 16B per lane; LDS dst is wave-uniform base + lane*16
#define GLD_LDS16(gp, lp)                                                     \
    __builtin_amdgcn_global_load_lds(                                         \
        (const __attribute__((address_space(1))) void*)(gp),                  \
        (__attribute__((address_space(3))) void*)(lp), 16, 0, 0)

// ---------------- Fused prologue (unchanged: at memory roofline) ----------------
__global__ __launch_bounds__(256) void prologue_kernel(
    const float4* __restrict__ x4, us4* __restrict__ xbf4,
    const float4* __restrict__ W4,
    const float4* __restrict__ A4,   // [16][1024] float4
    const float* __restrict__ B,     // [4096][16]
    const float* __restrict__ mag,   // [4096]
    unsigned short* __restrict__ wbf,
    float* __restrict__ scale) {
    const int tid = threadIdx.x;
    if (blockIdx.x < 512) {
        const int m0 = blockIdx.x * 8;
        __shared__ float Bs[8][16];
        __shared__ float red[32];
        if (tid < 128) Bs[tid >> 4][tid & 15] = B[m0 * 16 + tid];
        __syncthreads();
        float ss[8] = {};
        for (int c = tid; c < 1024; c += 256) {
            float4 a[16];
#pragma unroll
            for (int r = 0; r < 16; ++r) a[r] = A4[r * 1024 + c];
#pragma unroll
            for (int i = 0; i < 8; ++i) {
                float4 w = W4[(size_t)(m0 + i) * 1024 + c];
#pragma unroll
                for (int r = 0; r < 16; ++r) {
                    const float br = Bs[i][r];
                    w.x += br * a[r].x; w.y += br * a[r].y;
                    w.z += br * a[r].z; w.w += br * a[r].w;
                }
                ss[i] += w.x * w.x + w.y * w.y + w.z * w.z + w.w * w.w;
                us4 o; o[0] = bf_rne(w.x); o[1] = bf_rne(w.y);
                o[2] = bf_rne(w.z); o[3] = bf_rne(w.w);
                *(us4*)&wbf[(size_t)(m0 + i) * 4096 + c * 4] = o;
            }
        }
        const int lane = tid & 63, wv = tid >> 6;
#pragma unroll
        for (int i = 0; i < 8; ++i) {
            float v = ss[i];
#pragma unroll
            for (int off = 32; off > 0; off >>= 1) v += __shfl_down(v, off, 64);
            if (lane == 0) red[wv * 8 + i] = v;
        }
        __syncthreads();
        if (tid < 8) {
            float tot = red[tid] + red[8 + tid] + red[16 + tid] + red[24 + tid];
            scale[m0 + tid] = mag[m0 + tid] / sqrtf(tot);
        }
    } else {
        const size_t base = (size_t)(blockIdx.x - 512) * 1024 + tid;
#pragma unroll
        for (int j = 0; j < 4; ++j) {
            const size_t idx = base + j * 256;
            float4 a = x4[idx];
            us4 o;
            o[0] = bf_rne(a.x); o[1] = bf_rne(a.y);
            o[2] = bf_rne(a.z); o[3] = bf_rne(a.w);
            xbf4[idx] = o;
        }
    }
}

// ---------------- GEMM: C[8192][4096] = xbf @ wbf^T * scale ----------------
// 256x256 tile, BK=64, 8 waves (2M x 4N). Template-faithful 8-phase schedule:
// 2 K-tiles/iter (buf0=even tile, buf1=odd), 1 half-tile stage per phase,
// vmcnt(6) ONLY at phases 4 and 8 (3 half-tiles stay in flight; each load gets
// 3-7 phases to land -> covers vmem queuing). 24 ds_read_b128/wave/K-tile
// (B frags fully resident, no re-reads). XOR-swizzled LDS (conflict-free).
// Stage ledger (iter i, tiles t0=2i/t1=2i+1):
//   ph1: A1(t1)->buf1   [region free after iter i-1 ph7 barrier]
//   ph2: A0(t0+2)->buf0 [free after ph1]   ph3: B0(t0+2) [free after ph1]
//   ph4: B1(t0+2) [free after ph2]         ph5: A1(t0+2) [free after ph3]
//   ph6: A0(t1+2)->buf1 [free after ph5]   ph7: B0(t1+2) [free after ph5]
//   ph8: B1(t1+2) [free after ph6]
// W4 = vmcnt(6) leaves {A0,B0,B1}(t0+2) in flight => tile t1 fully landed.
// W8 = vmcnt(6) leaves {A0,B0,B1}(t1+2) in flight => tile t0+2 fully landed.
#define FENCE() asm volatile("" ::: "memory")
#define BAR()   do { FENCE(); __builtin_amdgcn_s_barrier(); FENCE(); } while (0)
#define VMW6()  asm volatile("s_waitcnt vmcnt(6)" ::: "memory")
#define VMW0()  asm volatile("s_waitcnt vmcnt(0)" ::: "memory")
#define LGW8()  asm volatile("s_waitcnt lgkmcnt(8)" ::: "memory")
#define LGW0()  asm volatile("s_waitcnt lgkmcnt(0)" ::: "memory")
#define PRIO1() __builtin_amdgcn_s_setprio(1)
#define PRIO0() __builtin_amdgcn_s_setprio(0)

__global__ __launch_bounds__(512, 2) void dora_gemm(
    const unsigned short* __restrict__ xbf,   // [8192][4096] bf16
    const unsigned short* __restrict__ wbf,   // [4096][4096] bf16
    const float* __restrict__ scale,          // [4096]
    float* __restrict__ out) {                // [8192][4096] fp32
    __shared__ __align__(16) unsigned short As[2][256 * 64];
    __shared__ __align__(16) unsigned short Bs[2][256 * 64];

    const int tid  = threadIdx.x;
    const int lane = tid & 63;
    const int w    = tid >> 6;     // wave 0..7
    const int wm   = w >> 2;       // 0..1
    const int wn   = w & 3;        // 0..3
    const int q    = lane >> 4;
    const int c15  = lane & 15;

    // XCD mapping: 8 XCDs x 64 blocks; each XCD owns an 8M x 8N tile square
    // (bijective over the 32x16 grid). Within XCD: M sweeps fastest -> 8
    // consecutive blocks share one B panel; A working set 16MB/XCD (vs 64MB).
    const int bid = blockIdx.x;
    const int xcd = bid & 7, sub = bid >> 3;
    const int tileM = (((xcd & 3) << 3) | (sub & 7)) << 8;   // 0..31 * 256
    const int tileN = (((xcd >> 2) << 3) | (sub >> 3)) << 8; // 0..15 * 256

    // staging: thread t, load j covers linear chunk c = j*512 + t of a half-tile
    // (128 rows x 64 bf16). row-in-half = c>>3, phys 16B chunk = c&7; XOR swizzle:
    // phys chunk p of row r holds logical chunk p ^ (r&7) -> pre-swizzled source.
    const int r0 = tid >> 3;              // 0..63
    const int lc = (tid & 7) ^ (r0 & 7);
    const size_t aoff = (size_t)(tileM + r0) * 4096 + lc * 8;
    const size_t boff = (size_t)(tileN + r0) * 4096 + lc * 8;
    const int ld0 = (w * 64) * 8;         // shorts; wave-uniform LDS base, j=0
    const int ld1 = (512 + w * 64) * 8;   // j=1 (+64 rows)

#define STAGE_A(d, h, k0) do {                                                            \
    GLD_LDS16(xbf + aoff + (size_t)((h) * 128) * 4096 + (k0),      &As[d][(h) * 8192 + ld0]); \
    GLD_LDS16(xbf + aoff + (size_t)((h) * 128 + 64) * 4096 + (k0), &As[d][(h) * 8192 + ld1]); \
} while (0)
#define STAGE_B(d, h, k0) do {                                                            \
    GLD_LDS16(wbf + boff + (size_t)((h) * 128) * 4096 + (k0),      &Bs[d][(h) * 8192 + ld0]); \
    GLD_LDS16(wbf + boff + (size_t)((h) * 128 + 64) * 4096 + (k0), &Bs[d][(h) * 8192 + ld1]); \
} while (0)

    s16x8 af[4][2];      // A frags, current half (held across 2 phases)
    s16x8 bfx[2][2][2];  // B frags [nh][nt][kc], fully resident per K-tile
    f32x4 acc[8][4] = {};

#define READ_A(d, mh) do {                                                    \
    _Pragma("unroll") for (int mt = 0; mt < 4; ++mt) {                        \
        const int row = (mh) * 128 + wm * 64 + mt * 16 + c15;                 \
        _Pragma("unroll") for (int kc = 0; kc < 2; ++kc) {                    \
            const int phys = (kc * 4 + q) ^ (row & 7);                        \
            af[mt][kc] = *(const s16x8*)&As[d][row * 64 + phys * 8];          \
        } } } while (0)
#define READ_B(d, nh) do {                                                    \
    _Pragma("unroll") for (int nt = 0; nt < 2; ++nt) {                        \
        const int row = (nh) * 128 + wn * 32 + nt * 16 + c15;                 \
        _Pragma("unroll") for (int kc = 0; kc < 2; ++kc) {                    \
            const int phys = (kc * 4 + q) ^ (row & 7);                        \
            bfx[nh][nt][kc] = *(const s16x8*)&Bs[d][row * 64 + phys * 8];     \
        } } } while (0)
#define MFMA_Q(mh, nh) do {                                                   \
    _Pragma("unroll") for (int mt = 0; mt < 4; ++mt)                          \
    _Pragma("unroll") for (int nt = 0; nt < 2; ++nt)                          \
    _Pragma("unroll") for (int kc = 0; kc < 2; ++kc)                          \
        acc[(mh) * 4 + mt][(nh) * 2 + nt] =                                   \
            __builtin_amdgcn_mfma_f32_16x16x32_bf16(                          \
                af[mt][kc], bfx[nh][nt][kc],                                  \
                acc[(mh) * 4 + mt][(nh) * 2 + nt], 0, 0, 0);                  \
} while (0)

    // prologue: tile0 full -> buf0, tile1 {A0,B0,B1} -> buf1 (A1(1) staged ph1)
    STAGE_A(0, 0, 0); STAGE_B(0, 0, 0); STAGE_B(0, 1, 0); STAGE_A(0, 1, 0);
    STAGE_A(1, 0, 64); STAGE_B(1, 0, 64); STAGE_B(1, 1, 64);
    VMW6(); BAR();   // tile0 landed; tile1's 3 half-tiles stay in flight

    for (int t0k = 0; t0k < 62 * 64; t0k += 128) {  // tiles t0=2i, t1=2i+1
        const int kA1 = t0k + 64;    // tile 2i+1 (its A1, staged ph1)
        const int kn2 = t0k + 128;   // tile 2i+2 -> buf0
        const int kn3 = t0k + 192;   // tile 2i+3 -> buf1
        // ---- K-tile t0 (buf0) ----
        // ph1: Q(0,0) — 12 ds_read
        READ_A(0, 0); READ_B(0, 0);
        STAGE_A(1, 1, kA1);
        LGW8(); BAR(); LGW0();
        PRIO1(); MFMA_Q(0, 0); PRIO0(); BAR();
        // ph2: Q(0,1) — 4 ds_read (A0 held)
        READ_B(0, 1);
        STAGE_A(0, 0, kn2);
        BAR(); LGW0();
        PRIO1(); MFMA_Q(0, 1); PRIO0(); BAR();
        // ph3: Q(1,1) — 8 ds_read (B1 held)
        READ_A(0, 1);
        STAGE_B(0, 0, kn2);
        BAR(); LGW0();
        PRIO1(); MFMA_Q(1, 1); PRIO0(); BAR();
        // ph4: Q(1,0) — 0 ds_read (A1, B0 resident); W4
        STAGE_B(0, 1, kn2);
        VMW6(); BAR();
        PRIO1(); MFMA_Q(1, 0); PRIO0(); BAR();
        // ---- K-tile t1 (buf1) ----
        // ph5: Q(0,0)
        READ_A(1, 0); READ_B(1, 0);
        STAGE_A(0, 1, kn2);
        LGW8(); BAR(); LGW0();
        PRIO1(); MFMA_Q(0, 0); PRIO0(); BAR();
        // ph6: Q(0,1)
        READ_B(1, 1);
        STAGE_A(1, 0, kn3);
        BAR(); LGW0();
        PRIO1(); MFMA_Q(0, 1); PRIO0(); BAR();
        // ph7: Q(1,1)
        READ_A(1, 1);
        STAGE_B(1, 0, kn3);
        BAR(); LGW0();
        PRIO1(); MFMA_Q(1, 1); PRIO0(); BAR();
        // ph8: Q(1,0); W8
        STAGE_B(1, 1, kn3);
        VMW6(); BAR();
        PRIO1(); MFMA_Q(1, 0); PRIO0(); BAR();
    }

    // ---- peeled tiles 62 (buf0) / 63 (buf1) ----
    // entering: tile62 landed (W8 of last iter); {A0,B0,B1}(63) in flight
    READ_A(0, 0); READ_B(0, 0);
    STAGE_A(1, 1, 63 * 64);          // A1(63)
    LGW8(); BAR(); LGW0();
    PRIO1(); MFMA_Q(0, 0); PRIO0(); BAR();
    READ_B(0, 1); BAR(); LGW0();
    PRIO1(); MFMA_Q(0, 1); PRIO0(); BAR();
    READ_A(0, 1); BAR(); LGW0();
    PRIO1(); MFMA_Q(1, 1); PRIO0(); BAR();
    VMW0(); BAR();                   // tile 63 fully landed
    PRIO1(); MFMA_Q(1, 0); PRIO0(); BAR();
    READ_A(1, 0); READ_B(1, 0); BAR(); LGW0();
    PRIO1(); MFMA_Q(0, 0); PRIO0(); BAR();
    READ_B(1, 1); BAR(); LGW0();
    PRIO1(); MFMA_Q(0, 1); PRIO0(); BAR();
    READ_A(1, 1); BAR(); LGW0();
    PRIO1(); MFMA_Q(1, 1); PRIO0();
    MFMA_Q(1, 0);

    // epilogue: C/D layout col=lane&15, row=(lane>>4)*4+reg ; scale by mag/norm
#pragma unroll
    for (int nh = 0; nh < 2; ++nh)
#pragma unroll
    for (int nt = 0; nt < 2; ++nt) {
        const int col = tileN + nh * 128 + wn * 32 + nt * 16 + c15;
        const float s = scale[col];
#pragma unroll
        for (int mh = 0; mh < 2; ++mh)
#pragma unroll
        for (int mt = 0; mt < 4; ++mt) {
            const int row0 = tileM + mh * 128 + wm * 64 + mt * 16 + q * 4;
#pragma unroll
            for (int r = 0; r < 4; ++r)
                out[(size_t)(row0 + r) * 4096 + col] = acc[mh * 4 + mt][nh * 2 + nt][r] * s;
        }
    }
}

extern "C" void kernel_launch(void* const* d_in, const int* in_sizes, int n_in,
                              void* d_out, int out_size, void* d_ws, size_t ws_size,
                              hipStream_t stream) {
    const float* x   = (const float*)d_in[0];   // [4,2048,4096]
    const float* W   = (const float*)d_in[1];   // [4096,4096]
    const float* A   = (const float*)d_in[2];   // [16,4096]
    const float* B   = (const float*)d_in[3];   // [4096,16]
    const float* mag = (const float*)d_in[4];   // [4096]
    float* out = (float*)d_out;

    const size_t XBF_BYTES = (size_t)8192 * 4096 * 2;  // 67,108,864
    const size_t WBF_BYTES = (size_t)4096 * 4096 * 2;  // 33,554,432
    const size_t NEEDED = XBF_BYTES + WBF_BYTES + 4096 * sizeof(float);
    if (ws_size < NEEDED) return;

    unsigned short* xbf = (unsigned short*)d_ws;
    unsigned short* wbf = (unsigned short*)((char*)d_ws + XBF_BYTES);
    float* scale = (float*)((char*)d_ws + XBF_BYTES + WBF_BYTES);

    prologue_kernel<<<8704, 256, 0, stream>>>((const float4*)x, (us4*)xbf,
                                              (const float4*)W, (const float4*)A,
                                              B, mag, wbf, scale);
    dora_gemm<<<512, 512, 0, stream>>>(xbf, wbf, scale, out);
}